// Round 1
// baseline (1128.881 us; speedup 1.0000x reference)
//
#include <hip/hip_runtime.h>
#include <math.h>

#define BB 2
#define SS 2048
#define EE 1024
#define HH 16
#define DD 64
#define YAT_EPS 1e-5f

// C[M,N] = A[M,K] @ W[N,K]^T + bias[N]   (fp32, all row-major)
__global__ __launch_bounds__(256) void gemm_bt(const float* __restrict__ A,
                                               const float* __restrict__ W,
                                               const float* __restrict__ bias,
                                               float* __restrict__ C,
                                               int M, int N, int K) {
    __shared__ float As[16][68];
    __shared__ float Ws[16][68];
    const int t = threadIdx.x;
    const int tx = t & 15, ty = t >> 4;
    const int m0 = blockIdx.y * 64, n0 = blockIdx.x * 64;
    const int ar = t >> 2, ac = (t & 3) * 4;   // 1 float4 per thread per tile
    float c[4][4] = {};
    for (int k0 = 0; k0 < K; k0 += 16) {
        float4 av = *(const float4*)&A[(size_t)(m0 + ar) * K + k0 + ac];
        float4 wv = *(const float4*)&W[(size_t)(n0 + ar) * K + k0 + ac];
        As[ac + 0][ar] = av.x; As[ac + 1][ar] = av.y;
        As[ac + 2][ar] = av.z; As[ac + 3][ar] = av.w;
        Ws[ac + 0][ar] = wv.x; Ws[ac + 1][ar] = wv.y;
        Ws[ac + 2][ar] = wv.z; Ws[ac + 3][ar] = wv.w;
        __syncthreads();
        #pragma unroll
        for (int k = 0; k < 16; ++k) {
            float4 a4 = *(const float4*)&As[k][ty * 4];
            float4 w4 = *(const float4*)&Ws[k][tx * 4];
            float aa[4] = {a4.x, a4.y, a4.z, a4.w};
            float ww[4] = {w4.x, w4.y, w4.z, w4.w};
            #pragma unroll
            for (int i = 0; i < 4; ++i)
                #pragma unroll
                for (int j = 0; j < 4; ++j)
                    c[i][j] += aa[i] * ww[j];
        }
        __syncthreads();
    }
    float4 bb = *(const float4*)&bias[n0 + tx * 4];
    #pragma unroll
    for (int i = 0; i < 4; ++i) {
        float4 o = make_float4(c[i][0] + bb.x, c[i][1] + bb.y,
                               c[i][2] + bb.z, c[i][3] + bb.w);
        *(float4*)&C[(size_t)(m0 + ty * 4 + i) * N + n0 + tx * 4] = o;
    }
}

// Flash-style YAT attention: one block = (b,h) x 64-row Q tile.
// scores = (qk)^2 / (||q||^2+||k||^2-2qk+eps) * scale ; softmax over k ; O = P.V
__global__ __launch_bounds__(256) void yat_attn(const float* __restrict__ q,
                                                const float* __restrict__ k,
                                                const float* __restrict__ v,
                                                const float* __restrict__ alphap,
                                                float* __restrict__ ctx) {
    __shared__ float Qs[64][68];   // [d][m]  (transposed)
    __shared__ float KV[64][68];   // K phase: [d][n] transposed; V phase: [kk][d] natural
    __shared__ float Ss[64][68];   // scores -> probabilities [m][n]
    __shared__ float sq[64], sk[64], m_i[64], l_i[64], arow[64];

    const int t = threadIdx.x;
    const int tx = t & 15, ty = t >> 4;
    const int qt = blockIdx.x, bh = blockIdx.y;
    const int b = bh / HH, h = bh % HH;
    const int hoff = h * DD;
    const int rowbase = b * SS;
    const float scale = powf(sqrtf((float)DD) / log1pf((float)DD), alphap[0]);

    // ---- load Q tile (transposed) ----
    #pragma unroll
    for (int i = 0; i < 4; ++i) {
        int idx = t + 256 * i;
        int r = idx >> 4, d4 = (idx & 15) * 4;
        float4 qv = *(const float4*)&q[(size_t)(rowbase + qt * 64 + r) * EE + hoff + d4];
        Qs[d4 + 0][r] = qv.x; Qs[d4 + 1][r] = qv.y;
        Qs[d4 + 2][r] = qv.z; Qs[d4 + 3][r] = qv.w;
    }
    __syncthreads();
    if (t < 64) {
        float s = 0.f;
        #pragma unroll 16
        for (int d = 0; d < 64; ++d) { float x = Qs[d][t]; s += x * x; }
        sq[t] = s;
        m_i[t] = -INFINITY;
        l_i[t] = 0.f;
    }

    float O[4][4] = {};

    for (int kt = 0; kt < SS / 64; ++kt) {
        __syncthreads();   // prev PV done with KV/Ss; sq/m_i/l_i ready on iter 0
        // ---- load K tile (transposed) ----
        #pragma unroll
        for (int i = 0; i < 4; ++i) {
            int idx = t + 256 * i;
            int r = idx >> 4, d4 = (idx & 15) * 4;
            float4 kv = *(const float4*)&k[(size_t)(rowbase + kt * 64 + r) * EE + hoff + d4];
            KV[d4 + 0][r] = kv.x; KV[d4 + 1][r] = kv.y;
            KV[d4 + 2][r] = kv.z; KV[d4 + 3][r] = kv.w;
        }
        __syncthreads();
        if (t < 64) {
            float s = 0.f;
            #pragma unroll 16
            for (int d = 0; d < 64; ++d) { float x = KV[d][t]; s += x * x; }
            sk[t] = s;
        }
        // ---- qk = Q.K^T (4x4 per thread) ----
        float c[4][4] = {};
        #pragma unroll 8
        for (int d = 0; d < 64; ++d) {
            float4 a4 = *(const float4*)&Qs[d][ty * 4];
            float4 k4 = *(const float4*)&KV[d][tx * 4];
            float aa[4] = {a4.x, a4.y, a4.z, a4.w};
            float kk4[4] = {k4.x, k4.y, k4.z, k4.w};
            #pragma unroll
            for (int i = 0; i < 4; ++i)
                #pragma unroll
                for (int j = 0; j < 4; ++j)
                    c[i][j] += aa[i] * kk4[j];
        }
        __syncthreads();   // all threads done reading KV(K); sk ready
        // ---- load V tile (natural) into KV ----
        #pragma unroll
        for (int i = 0; i < 4; ++i) {
            int idx = t + 256 * i;
            int r = idx >> 4, d4 = (idx & 15) * 4;
            *(float4*)&KV[r][d4] =
                *(const float4*)&v[(size_t)(rowbase + kt * 64 + r) * EE + hoff + d4];
        }
        // ---- YAT scores ----
        #pragma unroll
        for (int i = 0; i < 4; ++i) {
            float sqm = sq[ty * 4 + i];
            #pragma unroll
            for (int j = 0; j < 4; ++j) {
                float qkv = c[i][j];
                float dist = sqm + sk[tx * 4 + j] - 2.f * qkv;
                Ss[ty * 4 + i][tx * 4 + j] = (qkv * qkv) / (dist + YAT_EPS) * scale;
            }
        }
        __syncthreads();   // Ss + V ready
        // ---- online softmax: 4 threads per row ----
        {
            int r = t >> 2, qp = t & 3;
            float mx = -INFINITY;
            #pragma unroll
            for (int j = 0; j < 16; ++j) mx = fmaxf(mx, Ss[r][qp * 16 + j]);
            mx = fmaxf(mx, __shfl_xor(mx, 1));
            mx = fmaxf(mx, __shfl_xor(mx, 2));
            float mold = m_i[r];
            float mnew = fmaxf(mold, mx);
            float a = __expf(mold - mnew);
            float sum = 0.f;
            #pragma unroll
            for (int j = 0; j < 16; ++j) {
                float p = __expf(Ss[r][qp * 16 + j] - mnew);
                Ss[r][qp * 16 + j] = p;
                sum += p;
            }
            sum += __shfl_xor(sum, 1);
            sum += __shfl_xor(sum, 2);
            if (qp == 0) {
                m_i[r] = mnew;
                l_i[r] = l_i[r] * a + sum;
                arow[r] = a;
            }
        }
        __syncthreads();   // P + arow ready
        // ---- O = O*a + P.V ----
        float a_r[4];
        #pragma unroll
        for (int i = 0; i < 4; ++i) a_r[i] = arow[ty * 4 + i];
        #pragma unroll
        for (int i = 0; i < 4; ++i)
            #pragma unroll
            for (int j = 0; j < 4; ++j)
                O[i][j] *= a_r[i];
        #pragma unroll 8
        for (int kk = 0; kk < 64; ++kk) {
            float4 vv = *(const float4*)&KV[kk][tx * 4];
            float p[4];
            #pragma unroll
            for (int i = 0; i < 4; ++i) p[i] = Ss[ty * 4 + i][kk];
            #pragma unroll
            for (int i = 0; i < 4; ++i) {
                O[i][0] += p[i] * vv.x;
                O[i][1] += p[i] * vv.y;
                O[i][2] += p[i] * vv.z;
                O[i][3] += p[i] * vv.w;
            }
        }
    }
    // ---- epilogue: O / l, write context ----
    #pragma unroll
    for (int i = 0; i < 4; ++i) {
        float inv = 1.f / l_i[ty * 4 + i];
        float4 o = make_float4(O[i][0] * inv, O[i][1] * inv,
                               O[i][2] * inv, O[i][3] * inv);
        *(float4*)&ctx[(size_t)(rowbase + qt * 64 + ty * 4 + i) * EE + hoff + tx * 4] = o;
    }
}

extern "C" void kernel_launch(void* const* d_in, const int* in_sizes, int n_in,
                              void* d_out, int out_size, void* d_ws, size_t ws_size,
                              hipStream_t stream) {
    const float* x     = (const float*)d_in[0];
    const float* Wq    = (const float*)d_in[1];
    const float* bq    = (const float*)d_in[2];
    const float* Wk    = (const float*)d_in[3];
    const float* bk    = (const float*)d_in[4];
    const float* Wv    = (const float*)d_in[5];
    const float* bv    = (const float*)d_in[6];
    const float* Wo    = (const float*)d_in[7];
    const float* bo    = (const float*)d_in[8];
    const float* alpha = (const float*)d_in[9];
    float* out = (float*)d_out;
    float* ws  = (float*)d_ws;

    const int M = BB * SS;                 // 4096
    const size_t mat = (size_t)M * EE;     // 4 Mi elements
    float* qb = ws;
    float* kb = ws + mat;
    float* vb = ws + 2 * mat;
    float* cb = ws + 3 * mat;

    dim3 g(EE / 64, M / 64);
    gemm_bt<<<g, 256, 0, stream>>>(x, Wq, bq, qb, M, EE, EE);
    gemm_bt<<<g, 256, 0, stream>>>(x, Wk, bk, kb, M, EE, EE);
    gemm_bt<<<g, 256, 0, stream>>>(x, Wv, bv, vb, M, EE, EE);
    yat_attn<<<dim3(SS / 64, BB * HH), 256, 0, stream>>>(qb, kb, vb, alpha, cb);
    gemm_bt<<<g, 256, 0, stream>>>(cb, Wo, bo, out, M, EE, EE);
}

// Round 2
// 817.837 us; speedup vs baseline: 1.3803x; 1.3803x over previous
//
#include <hip/hip_runtime.h>
#include <math.h>

#define BB 2
#define SS 2048
#define EE 1024
#define HH 16
#define DD 64
#define YAT_EPS 1e-5f

typedef __attribute__((ext_vector_type(8))) short bf16x8;
typedef __attribute__((ext_vector_type(4))) float f32x4;
#define MFMA16(a, b, c) __builtin_amdgcn_mfma_f32_16x16x32_bf16((a), (b), (c), 0, 0, 0)

__device__ __forceinline__ unsigned short f2bf(float x) {
    unsigned int u = __float_as_uint(x);
    u += 0x7FFFu + ((u >> 16) & 1u);   // RNE
    return (unsigned short)(u >> 16);
}
__device__ __forceinline__ float bf2f(unsigned short h) {
    return __uint_as_float(((unsigned int)h) << 16);
}

// C = A[M,K] @ W[N,K]^T + bias.
// MODE 0: write fp32 Cf.
// MODE 1: write bf16 hi/lo in [B,H,S,D] layout + fp32 row norms (q/k path).
// MODE 2: write bf16 hi in transposed [B,H,D,S] layout (v path).
template <int MODE>
__global__ __launch_bounds__(256) void gemm_bt(const float* __restrict__ A,
                                               const float* __restrict__ W,
                                               const float* __restrict__ bias,
                                               float* __restrict__ Cf,
                                               unsigned short* __restrict__ Ohi,
                                               unsigned short* __restrict__ Olo,
                                               float* __restrict__ Onorm,
                                               int M, int N, int K) {
    __shared__ float As[16][68];
    __shared__ float Ws[16][68];
    const int t = threadIdx.x;
    const int tx = t & 15, ty = t >> 4;
    const int m0 = blockIdx.y * 64, n0 = blockIdx.x * 64;
    const int ar = t >> 2, ac = (t & 3) * 4;
    float c[4][4] = {};
    for (int k0 = 0; k0 < K; k0 += 16) {
        float4 av = *(const float4*)&A[(size_t)(m0 + ar) * K + k0 + ac];
        float4 wv = *(const float4*)&W[(size_t)(n0 + ar) * K + k0 + ac];
        As[ac + 0][ar] = av.x; As[ac + 1][ar] = av.y;
        As[ac + 2][ar] = av.z; As[ac + 3][ar] = av.w;
        Ws[ac + 0][ar] = wv.x; Ws[ac + 1][ar] = wv.y;
        Ws[ac + 2][ar] = wv.z; Ws[ac + 3][ar] = wv.w;
        __syncthreads();
        #pragma unroll
        for (int k = 0; k < 16; ++k) {
            float4 a4 = *(const float4*)&As[k][ty * 4];
            float4 w4 = *(const float4*)&Ws[k][tx * 4];
            float aa[4] = {a4.x, a4.y, a4.z, a4.w};
            float ww[4] = {w4.x, w4.y, w4.z, w4.w};
            #pragma unroll
            for (int i = 0; i < 4; ++i)
                #pragma unroll
                for (int j = 0; j < 4; ++j)
                    c[i][j] += aa[i] * ww[j];
        }
        __syncthreads();
    }
    float4 bb = *(const float4*)&bias[n0 + tx * 4];
    float bv[4] = {bb.x, bb.y, bb.z, bb.w};

    if (MODE == 0) {
        #pragma unroll
        for (int i = 0; i < 4; ++i) {
            float4 o = make_float4(c[i][0] + bv[0], c[i][1] + bv[1],
                                   c[i][2] + bv[2], c[i][3] + bv[3]);
            *(float4*)&Cf[(size_t)(m0 + ty * 4 + i) * N + n0 + tx * 4] = o;
        }
    } else {
        const int h = blockIdx.x;          // N==1024, 64-wide tiles => head id
        const int b = m0 >> 11;            // S==2048 rows per batch
        const int bh = b * HH + h;
        const int srow = (m0 & (SS - 1)) + ty * 4;
        #pragma unroll
        for (int i = 0; i < 4; ++i) {
            float v4[4];
            #pragma unroll
            for (int j = 0; j < 4; ++j) v4[j] = c[i][j] + bv[j];
            if (MODE == 1) {
                // row norm over full head dim (all 64 cols are in this block)
                float pn = v4[0]*v4[0] + v4[1]*v4[1] + v4[2]*v4[2] + v4[3]*v4[3];
                #pragma unroll
                for (int off = 1; off < 16; off <<= 1) pn += __shfl_xor(pn, off);
                if (tx == 0) Onorm[(size_t)bh * SS + srow + i] = pn;
                unsigned short h4[4], l4[4];
                #pragma unroll
                for (int j = 0; j < 4; ++j) {
                    h4[j] = f2bf(v4[j]);
                    l4[j] = f2bf(v4[j] - bf2f(h4[j]));
                }
                size_t o = ((size_t)bh * SS + srow + i) * DD + tx * 4;
                *(ushort4*)&Ohi[o] = make_ushort4(h4[0], h4[1], h4[2], h4[3]);
                *(ushort4*)&Olo[o] = make_ushort4(l4[0], l4[1], l4[2], l4[3]);
            } else {
                // MODE 2: transposed store vt[bh][d][s]
                #pragma unroll
                for (int j = 0; j < 4; ++j)
                    Ohi[((size_t)bh * DD + tx * 4 + j) * SS + srow + i] = f2bf(v4[j]);
            }
        }
    }
}

// MFMA flash attention. Block = 128 q-rows x (b,h); each of 4 waves owns 32
// q-rows with register-resident online softmax state. No __syncthreads.
__global__ __launch_bounds__(256, 2) void yat_attn_mfma(
        const unsigned short* __restrict__ qhi, const unsigned short* __restrict__ qlo,
        const unsigned short* __restrict__ khi, const unsigned short* __restrict__ klo,
        const unsigned short* __restrict__ vt,
        const float* __restrict__ sqn, const float* __restrict__ skn,
        const float* __restrict__ alphap, float* __restrict__ ctx) {
    // per-wave P buffer: 32 rows x stride 80 bf16 (160B rows: 16B-aligned,
    // conflict-at-floor for both C-layout writes and A-frag b128 reads)
    __shared__ __align__(16) unsigned short Ps[4 * 32 * 80];

    const int t = threadIdx.x;
    const int w = t >> 6, lane = t & 63;
    const int quad = lane >> 4, lr = lane & 15;
    const int qt = blockIdx.x, bh = blockIdx.y;
    const int b = bh >> 4, h = bh & 15;
    const int row0 = qt * 128 + w * 32;
    const float scale = powf(sqrtf((float)DD) / log1pf((float)DD), alphap[0]);
    unsigned short* myP = &Ps[w * 32 * 80];

    // ---- persistent Q fragments (hi/lo) ----
    bf16x8 qh[2][2], ql[2][2];
    #pragma unroll
    for (int mg = 0; mg < 2; ++mg)
        #pragma unroll
        for (int kd = 0; kd < 2; ++kd) {
            size_t o = ((size_t)bh * SS + row0 + mg * 16 + lr) * DD + kd * 32 + quad * 8;
            qh[mg][kd] = *(const bf16x8*)&qhi[o];
            ql[mg][kd] = *(const bf16x8*)&qlo[o];
        }
    float sqv[2][4];
    #pragma unroll
    for (int mg = 0; mg < 2; ++mg)
        #pragma unroll
        for (int r = 0; r < 4; ++r)
            sqv[mg][r] = sqn[(size_t)bh * SS + row0 + mg * 16 + quad * 4 + r];

    float m_r[2][4], l_r[2][4];
    f32x4 O[2][4];
    #pragma unroll
    for (int mg = 0; mg < 2; ++mg)
        #pragma unroll
        for (int r = 0; r < 4; ++r) {
            m_r[mg][r] = -INFINITY; l_r[mg][r] = 0.f;
        }
    #pragma unroll
    for (int mg = 0; mg < 2; ++mg)
        #pragma unroll
        for (int ns = 0; ns < 4; ++ns)
            O[mg][ns] = (f32x4){0.f, 0.f, 0.f, 0.f};

    for (int kt = 0; kt < SS / 64; ++kt) {
        const int kbase = kt * 64;
        // ---- K fragments + k norms ----
        bf16x8 kh[4][2], kl[4][2];
        float skv[4];
        #pragma unroll
        for (int ns = 0; ns < 4; ++ns) {
            size_t o = ((size_t)bh * SS + kbase + ns * 16 + lr) * DD + quad * 8;
            kh[ns][0] = *(const bf16x8*)&khi[o];
            kh[ns][1] = *(const bf16x8*)&khi[o + 32];
            kl[ns][0] = *(const bf16x8*)&klo[o];
            kl[ns][1] = *(const bf16x8*)&klo[o + 32];
            skv[ns] = skn[(size_t)bh * SS + kbase + ns * 16 + lr];
        }
        // ---- QK^T, 3-pass hi/lo split (~fp32 accuracy) ----
        f32x4 C[2][4];
        #pragma unroll
        for (int mg = 0; mg < 2; ++mg)
            #pragma unroll
            for (int ns = 0; ns < 4; ++ns) {
                f32x4 acc = (f32x4){0.f, 0.f, 0.f, 0.f};
                #pragma unroll
                for (int kd = 0; kd < 2; ++kd) {
                    acc = MFMA16(qh[mg][kd], kh[ns][kd], acc);
                    acc = MFMA16(qh[mg][kd], kl[ns][kd], acc);
                    acc = MFMA16(ql[mg][kd], kh[ns][kd], acc);
                }
                C[mg][ns] = acc;
            }
        // ---- V fragments (issue early for latency overlap) ----
        bf16x8 vf[4][2];
        #pragma unroll
        for (int ns = 0; ns < 4; ++ns)
            #pragma unroll
            for (int kk = 0; kk < 2; ++kk)
                vf[ns][kk] = *(const bf16x8*)&vt[((size_t)bh * DD + ns * 16 + lr) * SS
                                                 + kbase + kk * 32 + quad * 8];
        // ---- YAT scores + online softmax (per-wave, register state) ----
        #pragma unroll
        for (int mg = 0; mg < 2; ++mg) {
            float p[4][4], mx[4];
            #pragma unroll
            for (int r = 0; r < 4; ++r) mx[r] = -INFINITY;
            #pragma unroll
            for (int ns = 0; ns < 4; ++ns)
                #pragma unroll
                for (int r = 0; r < 4; ++r) {
                    float qk = C[mg][ns][r];
                    float dist = sqv[mg][r] + skv[ns] - 2.f * qk + YAT_EPS;
                    float s = qk * qk / dist * scale;
                    p[ns][r] = s;
                    mx[r] = fmaxf(mx[r], s);
                }
            #pragma unroll
            for (int r = 0; r < 4; ++r) {
                #pragma unroll
                for (int off = 1; off < 16; off <<= 1)
                    mx[r] = fmaxf(mx[r], __shfl_xor(mx[r], off));
            }
            float aa[4], rs[4];
            #pragma unroll
            for (int r = 0; r < 4; ++r) {
                float mnew = fmaxf(m_r[mg][r], mx[r]);
                aa[r] = __expf(m_r[mg][r] - mnew);
                m_r[mg][r] = mnew;
            }
            #pragma unroll
            for (int ns = 0; ns < 4; ++ns)
                #pragma unroll
                for (int r = 0; r < 4; ++r)
                    p[ns][r] = __expf(p[ns][r] - m_r[mg][r]);
            #pragma unroll
            for (int r = 0; r < 4; ++r) {
                rs[r] = p[0][r] + p[1][r] + p[2][r] + p[3][r];
                #pragma unroll
                for (int off = 1; off < 16; off <<= 1)
                    rs[r] += __shfl_xor(rs[r], off);
                l_r[mg][r] = l_r[mg][r] * aa[r] + rs[r];
            }
            // write P (bf16) to this wave's LDS slice; rescale O
            #pragma unroll
            for (int ns = 0; ns < 4; ++ns)
                #pragma unroll
                for (int r = 0; r < 4; ++r)
                    myP[(mg * 16 + quad * 4 + r) * 80 + ns * 16 + lr] = f2bf(p[ns][r]);
            #pragma unroll
            for (int ns = 0; ns < 4; ++ns)
                #pragma unroll
                for (int r = 0; r < 4; ++r)
                    O[mg][ns][r] *= aa[r];
        }
        // ---- PV: P (A-frag from LDS) x V (B-frag) ----
        #pragma unroll
        for (int mg = 0; mg < 2; ++mg) {
            bf16x8 pf[2];
            #pragma unroll
            for (int kk = 0; kk < 2; ++kk)
                pf[kk] = *(const bf16x8*)&myP[(mg * 16 + lr) * 80 + kk * 32 + quad * 8];
            #pragma unroll
            for (int ns = 0; ns < 4; ++ns)
                #pragma unroll
                for (int kk = 0; kk < 2; ++kk)
                    O[mg][ns] = MFMA16(pf[kk], vf[ns][kk], O[mg][ns]);
        }
    }
    // ---- epilogue ----
    #pragma unroll
    for (int mg = 0; mg < 2; ++mg)
        #pragma unroll
        for (int r = 0; r < 4; ++r) {
            float inv = 1.f / l_r[mg][r];
            int row = row0 + mg * 16 + quad * 4 + r;
            #pragma unroll
            for (int ns = 0; ns < 4; ++ns)
                ctx[((size_t)b * SS + row) * EE + h * DD + ns * 16 + lr] =
                    O[mg][ns][r] * inv;
        }
}

extern "C" void kernel_launch(void* const* d_in, const int* in_sizes, int n_in,
                              void* d_out, int out_size, void* d_ws, size_t ws_size,
                              hipStream_t stream) {
    const float* x     = (const float*)d_in[0];
    const float* Wq    = (const float*)d_in[1];
    const float* bq    = (const float*)d_in[2];
    const float* Wk    = (const float*)d_in[3];
    const float* bk    = (const float*)d_in[4];
    const float* Wv    = (const float*)d_in[5];
    const float* bv    = (const float*)d_in[6];
    const float* Wo    = (const float*)d_in[7];
    const float* bo    = (const float*)d_in[8];
    const float* alpha = (const float*)d_in[9];
    float* out = (float*)d_out;
    char* ws = (char*)d_ws;

    const int M = BB * SS;                 // 4096
    const size_t MB = 1u << 20;
    unsigned short* qhi = (unsigned short*)(ws + 0 * MB);
    unsigned short* qlo = (unsigned short*)(ws + 8 * MB);
    unsigned short* khi = (unsigned short*)(ws + 16 * MB);
    unsigned short* klo = (unsigned short*)(ws + 24 * MB);
    unsigned short* vt  = (unsigned short*)(ws + 32 * MB);
    float* sqn = (float*)(ws + 40 * MB);
    float* skn = (float*)(ws + 41 * MB);
    float* cb  = (float*)(ws + 42 * MB);   // 16 MB fp32 context

    dim3 g(EE / 64, M / 64);
    gemm_bt<1><<<g, 256, 0, stream>>>(x, Wq, bq, nullptr, qhi, qlo, sqn, M, EE, EE);
    gemm_bt<1><<<g, 256, 0, stream>>>(x, Wk, bk, nullptr, khi, klo, skn, M, EE, EE);
    gemm_bt<2><<<g, 256, 0, stream>>>(x, Wv, bv, nullptr, vt, nullptr, nullptr, M, EE, EE);
    yat_attn_mfma<<<dim3(SS / 128, BB * HH), 256, 0, stream>>>(
        qhi, qlo, khi, klo, vt, sqn, skn, alpha, cb);
    gemm_bt<0><<<g, 256, 0, stream>>>(cb, Wo, bo, out, nullptr, nullptr, nullptr, M, EE, EE);
}

// Round 3
// 454.531 us; speedup vs baseline: 2.4836x; 1.7993x over previous
//
#include <hip/hip_runtime.h>
#include <math.h>

#define BB 2
#define SS 2048
#define EE 1024
#define HH 16
#define DD 64
#define YAT_EPS 1e-5f

typedef __attribute__((ext_vector_type(8))) short bf16x8;
typedef __attribute__((ext_vector_type(4))) float f32x4;
#define MFMA16(a, b, c) __builtin_amdgcn_mfma_f32_16x16x32_bf16((a), (b), (c), 0, 0, 0)

__device__ __forceinline__ unsigned short f2bf(float x) {
    unsigned int u = __float_as_uint(x);
    u += 0x7FFFu + ((u >> 16) & 1u);   // RNE
    return (unsigned short)(u >> 16);
}
__device__ __forceinline__ float bf2f(unsigned short h) {
    return __uint_as_float(((unsigned int)h) << 16);
}

__device__ __forceinline__ void async_ld16(void* lds, const void* g) {
    __builtin_amdgcn_global_load_lds(
        (const __attribute__((address_space(1))) unsigned int*)g,
        (__attribute__((address_space(3))) unsigned int*)lds, 16, 0, 0);
}

// fp32 -> bf16 hi/lo split (grid covers n/4 float4s exactly)
__global__ __launch_bounds__(256) void split_f32(const float* __restrict__ in,
                                                 unsigned short* __restrict__ hi,
                                                 unsigned short* __restrict__ lo,
                                                 int n4) {
    int i = blockIdx.x * 256 + threadIdx.x;
    if (i >= n4) return;
    float4 v = ((const float4*)in)[i];
    ushort4 h, l;
    h.x = f2bf(v.x); l.x = f2bf(v.x - bf2f(h.x));
    h.y = f2bf(v.y); l.y = f2bf(v.y - bf2f(h.y));
    h.z = f2bf(v.z); l.z = f2bf(v.z - bf2f(h.z));
    h.w = f2bf(v.w); l.w = f2bf(v.w - bf2f(h.w));
    ((ushort4*)hi)[i] = h;
    ((ushort4*)lo)[i] = l;
}

// 3-pass (hi/lo) bf16 MFMA GEMM: C[M,N] = A[M,K] @ B[N,K]^T + bias.
// m97 structure: 128x128 tile, BK=32, global_load_lds staging (each wave
// owns one of the 4 LDS tiles), 48 MFMA per wave K-step.
// MODE 0: fp32 out + bias (O-projection).
// MODE 1: fused QKV epilogue (N=3072): q/k -> bf16 hi/lo [B,H,S,D] + norms;
//         v -> bf16 [B,H,S,D].
template <int MODE>
__global__ __launch_bounds__(256, 2) void gemm3p(
        const unsigned short* __restrict__ Ahi, const unsigned short* __restrict__ Alo,
        const unsigned short* __restrict__ Bhi, const unsigned short* __restrict__ Blo,
        const float* __restrict__ bq, const float* __restrict__ bk,
        const float* __restrict__ bv,
        float* __restrict__ Cf,
        unsigned short* __restrict__ qhi, unsigned short* __restrict__ qlo,
        unsigned short* __restrict__ khi, unsigned short* __restrict__ klo,
        unsigned short* __restrict__ v_sd,
        float* __restrict__ sqn, float* __restrict__ skn,
        int M, int N, int K) {
    __shared__ __align__(16) unsigned short LA_hi[128 * 32];
    __shared__ __align__(16) unsigned short LA_lo[128 * 32];
    __shared__ __align__(16) unsigned short LB_hi[128 * 32];
    __shared__ __align__(16) unsigned short LB_lo[128 * 32];

    const int t = threadIdx.x;
    const int w = t >> 6, lane = t & 63;
    const int quad = lane >> 4, lr = lane & 15;
    const int wy = w & 1, wx = w >> 1;
    const int m0 = blockIdx.y * 128, n0 = blockIdx.x * 128;

    // staging assignment: wave w stages one whole 128x32 tile
    const unsigned short* gsrc;
    unsigned short* ldst;
    if (w == 0)      { gsrc = Ahi + (size_t)m0 * K; ldst = LA_hi; }
    else if (w == 1) { gsrc = Alo + (size_t)m0 * K; ldst = LA_lo; }
    else if (w == 2) { gsrc = Bhi + (size_t)n0 * K; ldst = LB_hi; }
    else             { gsrc = Blo + (size_t)n0 * K; ldst = LB_lo; }
    const unsigned short* gl = gsrc + (size_t)(lane >> 2) * K + (lane & 3) * 8;

    f32x4 acc[4][4];
    #pragma unroll
    for (int i = 0; i < 4; ++i)
        #pragma unroll
        for (int j = 0; j < 4; ++j)
            acc[i][j] = (f32x4){0.f, 0.f, 0.f, 0.f};

    for (int k0 = 0; k0 < K; k0 += 32) {
        __syncthreads();
        #pragma unroll
        for (int i = 0; i < 8; ++i)
            async_ld16(ldst + i * 512, gl + (size_t)i * 16 * K + k0);
        __syncthreads();
        bf16x8 ah[4], al[4], bh_[4], bl_[4];
        #pragma unroll
        for (int i = 0; i < 4; ++i) {
            ah[i]  = *(const bf16x8*)&LA_hi[(wy * 64 + i * 16 + lr) * 32 + quad * 8];
            al[i]  = *(const bf16x8*)&LA_lo[(wy * 64 + i * 16 + lr) * 32 + quad * 8];
            bh_[i] = *(const bf16x8*)&LB_hi[(wx * 64 + i * 16 + lr) * 32 + quad * 8];
            bl_[i] = *(const bf16x8*)&LB_lo[(wx * 64 + i * 16 + lr) * 32 + quad * 8];
        }
        #pragma unroll
        for (int mg = 0; mg < 4; ++mg)
            #pragma unroll
            for (int ns = 0; ns < 4; ++ns) {
                f32x4 a = acc[mg][ns];
                a = MFMA16(ah[mg], bh_[ns], a);
                a = MFMA16(ah[mg], bl_[ns], a);
                a = MFMA16(al[mg], bh_[ns], a);
                acc[mg][ns] = a;
            }
    }

    const int ng = n0 + wx * 64;
    if (MODE == 0) {
        float bias_v[4];
        #pragma unroll
        for (int ns = 0; ns < 4; ++ns) bias_v[ns] = bq[ng + ns * 16 + lr];
        #pragma unroll
        for (int mg = 0; mg < 4; ++mg)
            #pragma unroll
            for (int r = 0; r < 4; ++r) {
                int m = m0 + wy * 64 + mg * 16 + quad * 4 + r;
                #pragma unroll
                for (int ns = 0; ns < 4; ++ns)
                    Cf[(size_t)m * N + ng + ns * 16 + lr] = acc[mg][ns][r] + bias_v[ns];
            }
    } else {
        const int path = ng >> 10;         // 0=q 1=k 2=v
        const int c = ng & 1023;
        const int h = c >> 6;
        const float* bias = path == 0 ? bq : path == 1 ? bk : bv;
        unsigned short* hi_p = path == 0 ? qhi : khi;
        unsigned short* lo_p = path == 0 ? qlo : klo;
        float* nrm = path == 0 ? sqn : skn;
        float bias_v[4];
        #pragma unroll
        for (int ns = 0; ns < 4; ++ns) bias_v[ns] = bias[c + ns * 16 + lr];
        #pragma unroll
        for (int mg = 0; mg < 4; ++mg)
            #pragma unroll
            for (int r = 0; r < 4; ++r) {
                int m = m0 + wy * 64 + mg * 16 + quad * 4 + r;
                int b = m >> 11, s = m & (SS - 1);
                size_t base = ((size_t)(b * HH + h) * SS + s) * DD;
                float v4[4];
                #pragma unroll
                for (int ns = 0; ns < 4; ++ns) v4[ns] = acc[mg][ns][r] + bias_v[ns];
                if (path < 2) {
                    float pn = v4[0] * v4[0] + v4[1] * v4[1] + v4[2] * v4[2] + v4[3] * v4[3];
                    #pragma unroll
                    for (int off = 1; off < 16; off <<= 1) pn += __shfl_xor(pn, off);
                    if (lr == 0) nrm[(size_t)(b * HH + h) * SS + s] = pn;
                    #pragma unroll
                    for (int ns = 0; ns < 4; ++ns) {
                        unsigned short hv = f2bf(v4[ns]);
                        hi_p[base + ns * 16 + lr] = hv;
                        lo_p[base + ns * 16 + lr] = f2bf(v4[ns] - bf2f(hv));
                    }
                } else {
                    #pragma unroll
                    for (int ns = 0; ns < 4; ++ns)
                        v_sd[base + ns * 16 + lr] = f2bf(v4[ns]);
                }
            }
    }
}

// [bh][s][d] -> [bh][d][s] bf16 transpose, 64x64 LDS tiles
__global__ __launch_bounds__(256) void transpose_v(const unsigned short* __restrict__ v_sd,
                                                   unsigned short* __restrict__ vt) {
    __shared__ unsigned short T[64][65];
    const int t = threadIdx.x;
    const int bh = blockIdx.y, s0 = blockIdx.x * 64;
    {
        int sl = t >> 2, d4 = (t & 3) * 16;
        const unsigned short* src = &v_sd[((size_t)bh * SS + s0 + sl) * DD + d4];
        bf16x8 a = *(const bf16x8*)src;
        bf16x8 b = *(const bf16x8*)(src + 8);
        #pragma unroll
        for (int j = 0; j < 8; ++j) {
            T[sl][d4 + j] = (unsigned short)a[j];
            T[sl][d4 + 8 + j] = (unsigned short)b[j];
        }
    }
    __syncthreads();
    {
        int dl = t >> 2, s4 = (t & 3) * 16;
        bf16x8 a, b;
        #pragma unroll
        for (int j = 0; j < 8; ++j) {
            a[j] = (short)T[s4 + j][dl];
            b[j] = (short)T[s4 + 8 + j][dl];
        }
        unsigned short* dst = &vt[((size_t)bh * DD + dl) * SS + s0 + s4];
        *(bf16x8*)dst = a;
        *(bf16x8*)(dst + 8) = b;
    }
}

// MFMA flash attention (unchanged from round 2 except bf16 hi/lo ctx output).
__global__ __launch_bounds__(256, 2) void yat_attn_mfma(
        const unsigned short* __restrict__ qhi, const unsigned short* __restrict__ qlo,
        const unsigned short* __restrict__ khi, const unsigned short* __restrict__ klo,
        const unsigned short* __restrict__ vt,
        const float* __restrict__ sqn, const float* __restrict__ skn,
        const float* __restrict__ alphap,
        unsigned short* __restrict__ ctxhi, unsigned short* __restrict__ ctxlo) {
    __shared__ __align__(16) unsigned short Ps[4 * 32 * 80];

    const int t = threadIdx.x;
    const int w = t >> 6, lane = t & 63;
    const int quad = lane >> 4, lr = lane & 15;
    const int qt = blockIdx.x, bh = blockIdx.y;
    const int b = bh >> 4, h = bh & 15;
    const int row0 = qt * 128 + w * 32;
    const float scale = powf(sqrtf((float)DD) / log1pf((float)DD), alphap[0]);
    unsigned short* myP = &Ps[w * 32 * 80];

    bf16x8 qh[2][2], ql[2][2];
    #pragma unroll
    for (int mg = 0; mg < 2; ++mg)
        #pragma unroll
        for (int kd = 0; kd < 2; ++kd) {
            size_t o = ((size_t)bh * SS + row0 + mg * 16 + lr) * DD + kd * 32 + quad * 8;
            qh[mg][kd] = *(const bf16x8*)&qhi[o];
            ql[mg][kd] = *(const bf16x8*)&qlo[o];
        }
    float sqv[2][4];
    #pragma unroll
    for (int mg = 0; mg < 2; ++mg)
        #pragma unroll
        for (int r = 0; r < 4; ++r)
            sqv[mg][r] = sqn[(size_t)bh * SS + row0 + mg * 16 + quad * 4 + r];

    float m_r[2][4], l_r[2][4];
    f32x4 O[2][4];
    #pragma unroll
    for (int mg = 0; mg < 2; ++mg)
        #pragma unroll
        for (int r = 0; r < 4; ++r) { m_r[mg][r] = -INFINITY; l_r[mg][r] = 0.f; }
    #pragma unroll
    for (int mg = 0; mg < 2; ++mg)
        #pragma unroll
        for (int ns = 0; ns < 4; ++ns)
            O[mg][ns] = (f32x4){0.f, 0.f, 0.f, 0.f};

    for (int kt = 0; kt < SS / 64; ++kt) {
        const int kbase = kt * 64;
        bf16x8 kh[4][2], kl[4][2];
        float skv[4];
        #pragma unroll
        for (int ns = 0; ns < 4; ++ns) {
            size_t o = ((size_t)bh * SS + kbase + ns * 16 + lr) * DD + quad * 8;
            kh[ns][0] = *(const bf16x8*)&khi[o];
            kh[ns][1] = *(const bf16x8*)&khi[o + 32];
            kl[ns][0] = *(const bf16x8*)&klo[o];
            kl[ns][1] = *(const bf16x8*)&klo[o + 32];
            skv[ns] = skn[(size_t)bh * SS + kbase + ns * 16 + lr];
        }
        f32x4 C[2][4];
        #pragma unroll
        for (int mg = 0; mg < 2; ++mg)
            #pragma unroll
            for (int ns = 0; ns < 4; ++ns) {
                f32x4 acc = (f32x4){0.f, 0.f, 0.f, 0.f};
                #pragma unroll
                for (int kd = 0; kd < 2; ++kd) {
                    acc = MFMA16(qh[mg][kd], kh[ns][kd], acc);
                    acc = MFMA16(qh[mg][kd], kl[ns][kd], acc);
                    acc = MFMA16(ql[mg][kd], kh[ns][kd], acc);
                }
                C[mg][ns] = acc;
            }
        bf16x8 vf[4][2];
        #pragma unroll
        for (int ns = 0; ns < 4; ++ns)
            #pragma unroll
            for (int kk = 0; kk < 2; ++kk)
                vf[ns][kk] = *(const bf16x8*)&vt[((size_t)bh * DD + ns * 16 + lr) * SS
                                                 + kbase + kk * 32 + quad * 8];
        #pragma unroll
        for (int mg = 0; mg < 2; ++mg) {
            float p[4][4], mx[4];
            #pragma unroll
            for (int r = 0; r < 4; ++r) mx[r] = -INFINITY;
            #pragma unroll
            for (int ns = 0; ns < 4; ++ns)
                #pragma unroll
                for (int r = 0; r < 4; ++r) {
                    float qk = C[mg][ns][r];
                    float dist = sqv[mg][r] + skv[ns] - 2.f * qk + YAT_EPS;
                    float s = qk * qk / dist * scale;
                    p[ns][r] = s;
                    mx[r] = fmaxf(mx[r], s);
                }
            #pragma unroll
            for (int r = 0; r < 4; ++r) {
                #pragma unroll
                for (int off = 1; off < 16; off <<= 1)
                    mx[r] = fmaxf(mx[r], __shfl_xor(mx[r], off));
            }
            float aa[4], rs[4];
            #pragma unroll
            for (int r = 0; r < 4; ++r) {
                float mnew = fmaxf(m_r[mg][r], mx[r]);
                aa[r] = __expf(m_r[mg][r] - mnew);
                m_r[mg][r] = mnew;
            }
            #pragma unroll
            for (int ns = 0; ns < 4; ++ns)
                #pragma unroll
                for (int r = 0; r < 4; ++r)
                    p[ns][r] = __expf(p[ns][r] - m_r[mg][r]);
            #pragma unroll
            for (int r = 0; r < 4; ++r) {
                rs[r] = p[0][r] + p[1][r] + p[2][r] + p[3][r];
                #pragma unroll
                for (int off = 1; off < 16; off <<= 1)
                    rs[r] += __shfl_xor(rs[r], off);
                l_r[mg][r] = l_r[mg][r] * aa[r] + rs[r];
            }
            #pragma unroll
            for (int ns = 0; ns < 4; ++ns)
                #pragma unroll
                for (int r = 0; r < 4; ++r)
                    myP[(mg * 16 + quad * 4 + r) * 80 + ns * 16 + lr] = f2bf(p[ns][r]);
            #pragma unroll
            for (int ns = 0; ns < 4; ++ns)
                #pragma unroll
                for (int r = 0; r < 4; ++r)
                    O[mg][ns][r] *= aa[r];
        }
        #pragma unroll
        for (int mg = 0; mg < 2; ++mg) {
            bf16x8 pf[2];
            #pragma unroll
            for (int kk = 0; kk < 2; ++kk)
                pf[kk] = *(const bf16x8*)&myP[(mg * 16 + lr) * 80 + kk * 32 + quad * 8];
            #pragma unroll
            for (int ns = 0; ns < 4; ++ns)
                #pragma unroll
                for (int kk = 0; kk < 2; ++kk)
                    O[mg][ns] = MFMA16(pf[kk], vf[ns][kk], O[mg][ns]);
        }
    }
    #pragma unroll
    for (int mg = 0; mg < 2; ++mg)
        #pragma unroll
        for (int r = 0; r < 4; ++r) {
            float inv = 1.f / l_r[mg][r];
            int row = row0 + mg * 16 + quad * 4 + r;
            #pragma unroll
            for (int ns = 0; ns < 4; ++ns) {
                float o = O[mg][ns][r] * inv;
                size_t idx = ((size_t)b * SS + row) * EE + h * DD + ns * 16 + lr;
                unsigned short hv = f2bf(o);
                ctxhi[idx] = hv;
                ctxlo[idx] = f2bf(o - bf2f(hv));
            }
        }
}

extern "C" void kernel_launch(void* const* d_in, const int* in_sizes, int n_in,
                              void* d_out, int out_size, void* d_ws, size_t ws_size,
                              hipStream_t stream) {
    const float* x     = (const float*)d_in[0];
    const float* Wq    = (const float*)d_in[1];
    const float* bq    = (const float*)d_in[2];
    const float* Wk    = (const float*)d_in[3];
    const float* bk    = (const float*)d_in[4];
    const float* Wv    = (const float*)d_in[5];
    const float* bv    = (const float*)d_in[6];
    const float* Wo    = (const float*)d_in[7];
    const float* bo    = (const float*)d_in[8];
    const float* alpha = (const float*)d_in[9];
    float* out = (float*)d_out;
    char* ws = (char*)d_ws;

    const int M = BB * SS;                 // 4096
    const size_t MB = 1u << 20;
    // layout (MB offsets); aliases are safe per pipeline order:
    unsigned short* xhi  = (unsigned short*)(ws + 0 * MB);   // later: ctxhi
    unsigned short* xlo  = (unsigned short*)(ws + 8 * MB);   // later: ctxlo
    unsigned short* Whi  = (unsigned short*)(ws + 16 * MB);  // 6 MB (qkv concat)
    unsigned short* Wlo  = (unsigned short*)(ws + 22 * MB);  // 6 MB
    unsigned short* vt   = (unsigned short*)(ws + 16 * MB);  // reuses dead Whi/Wlo
    unsigned short* Wohi = (unsigned short*)(ws + 28 * MB);
    unsigned short* Wolo = (unsigned short*)(ws + 30 * MB);
    unsigned short* qhi  = (unsigned short*)(ws + 32 * MB);
    unsigned short* qlo  = (unsigned short*)(ws + 40 * MB);
    unsigned short* khi  = (unsigned short*)(ws + 48 * MB);
    unsigned short* klo  = (unsigned short*)(ws + 56 * MB);
    unsigned short* v_sd = (unsigned short*)(ws + 64 * MB);
    float* sqn = (float*)(ws + 72 * MB);
    float* skn = (float*)(ws + 72 * MB + 256 * 1024);
    unsigned short* ctxhi = xhi;
    unsigned short* ctxlo = xlo;

    const int nX = M * EE / 4, nW = EE * EE / 4;
    split_f32<<<nX / 256, 256, 0, stream>>>(x, xhi, xlo, nX);
    split_f32<<<nW / 256, 256, 0, stream>>>(Wq, Whi, Wlo, nW);
    split_f32<<<nW / 256, 256, 0, stream>>>(Wk, Whi + (size_t)EE * EE, Wlo + (size_t)EE * EE, nW);
    split_f32<<<nW / 256, 256, 0, stream>>>(Wv, Whi + 2 * (size_t)EE * EE, Wlo + 2 * (size_t)EE * EE, nW);
    split_f32<<<nW / 256, 256, 0, stream>>>(Wo, Wohi, Wolo, nW);

    gemm3p<1><<<dim3(3 * EE / 128, M / 128), 256, 0, stream>>>(
        xhi, xlo, Whi, Wlo, bq, bk, bv, nullptr,
        qhi, qlo, khi, klo, v_sd, sqn, skn, M, 3 * EE, EE);

    transpose_v<<<dim3(SS / 64, BB * HH), 256, 0, stream>>>(v_sd, vt);

    yat_attn_mfma<<<dim3(SS / 128, BB * HH), 256, 0, stream>>>(
        qhi, qlo, khi, klo, vt, sqn, skn, alpha, ctxhi, ctxlo);

    gemm3p<0><<<dim3(EE / 128, M / 128), 256, 0, stream>>>(
        ctxhi, ctxlo, Wohi, Wolo, bo, nullptr, nullptr, out,
        nullptr, nullptr, nullptr, nullptr, nullptr, nullptr, nullptr, M, EE, EE);
}